// Round 3
// baseline (296.963 us; speedup 1.0000x reference)
//
#include <hip/hip_runtime.h>
#include <hip/hip_bf16.h>

#define N_NODES 79
#define RAW_FEAT 26
#define D_IN 32
#define D_OUT 64
#define HIDDEN 256
#define N_EDGES 3000
#define BATCH 256
#define M_ROWS (BATCH * N_NODES)   // 20224

// ---------------------------------------------------------------------------
// k_prep: blocks 0-7 transpose W1 [256][97]->W1t[100][256];
//         blocks 8-23 transpose W2 [256][256]->W2t[256][256];
//         block 24 builds CSR by dst (batch-invariant topology).
// ---------------------------------------------------------------------------
__global__ __launch_bounds__(256) void k_prep(
    const float* __restrict__ W1, const float* __restrict__ W2,
    const int* __restrict__ ei, const float* __restrict__ ew,
    float* __restrict__ W1t, float* __restrict__ W2t,
    int* __restrict__ rp, int* __restrict__ csr_src,
    int* __restrict__ csr_dst, float* __restrict__ csr_ew)
{
    __shared__ float tile[64][65];
    __shared__ int cnt[N_NODES];
    __shared__ int base[N_NODES + 1];
    const int tid = threadIdx.x, bid = blockIdx.x;

    if (bid < 24) {
        const float* in; float* out; int C, Cpad, kb, rb;
        if (bid < 8) { in = W1; out = W1t; C = 97; Cpad = 100;
                       kb = (bid & 1) * 64; rb = (bid >> 1) * 64; }
        else         { int b = bid - 8; in = W2; out = W2t; C = 256; Cpad = 256;
                       kb = (b & 3) * 64; rb = (b >> 2) * 64; }
        for (int i = tid; i < 4096; i += 256) {
            int rr = i >> 6, kk = i & 63;
            int r = rb + rr, k = kb + kk;
            tile[rr][kk] = (k < C) ? in[r * C + k] : 0.f;
        }
        __syncthreads();
        for (int i = tid; i < 4096; i += 256) {
            int kk = i >> 6, rr = i & 63;
            int k = kb + kk, r = rb + rr;
            if (k < Cpad) out[(size_t)k * HIDDEN + r] = tile[rr][kk];
        }
        return;
    }

    // ---- CSR build (one block)
    if (tid < N_NODES) cnt[tid] = 0;
    __syncthreads();
    for (int e = tid; e < N_EDGES; e += 256) atomicAdd(&cnt[ei[N_EDGES + e]], 1);
    __syncthreads();
    if (tid == 0) {
        int run = 0;
        for (int n = 0; n < N_NODES; ++n) { base[n] = run; run += cnt[n]; }
        base[N_NODES] = run;
    }
    __syncthreads();
    if (tid < N_NODES + 1) rp[tid] = base[tid];
    if (tid < N_NODES) cnt[tid] = base[tid];   // cursor
    __syncthreads();
    for (int e = tid; e < N_EDGES; e += 256) {
        int d = ei[N_EDGES + e];
        int p = atomicAdd(&cnt[d], 1);
        csr_src[p] = ei[e];
        csr_dst[p] = d;
        csr_ew[p]  = ew[e];
    }
}

// ---------------------------------------------------------------------------
// K1: TransformerConv per batch element (one block per batch, 1 block/CU).
// CSR gather aggregation; edge term folded: agg = sum w*v[src] + csum*We.
// Rows stride 68 floats (17 f4) so random-row f4 reads spread banks.
// ---------------------------------------------------------------------------
__global__ __launch_bounds__(512) void k1_conv(
    const float* __restrict__ state, const float* __restrict__ pos,
    const int* __restrict__ rp_g, const int* __restrict__ csrc_g,
    const int* __restrict__ cdst_g, const float* __restrict__ cew_g,
    const float* __restrict__ Wq, const float* __restrict__ bq,
    const float* __restrict__ Wk, const float* __restrict__ bk,
    const float* __restrict__ Wv, const float* __restrict__ bv,
    const float* __restrict__ We, const float* __restrict__ Wsk,
    const float* __restrict__ bsk,
    float* __restrict__ out1_ws, float* __restrict__ ta_ws)
{
    __shared__ __align__(16) float xs[N_NODES * 32];
    __shared__ __align__(16) float qs [N_NODES * 68];
    __shared__ __align__(16) float kss[N_NODES * 68];
    __shared__ __align__(16) float vss[N_NODES * 68];
    __shared__ __align__(16) float o1s[N_NODES * 68];
    __shared__ __align__(16) float alpha[N_EDGES];      // raw -> exp -> w
    __shared__ __align__(16) float ewc[N_EDGES];
    __shared__ unsigned short srcs[N_EDGES], dsts[N_EDGES];
    __shared__ int   rp_s[N_NODES + 1];
    __shared__ __align__(16) float eW[64];
    __shared__ float qWe[N_NODES];
    __shared__ float csum_s[N_NODES];
    __shared__ int   amaxI[N_NODES];
    __shared__ float dens[N_NODES];

    const int b = blockIdx.x, tid = threadIdx.x;

    // ---- stage
    for (int t = tid; t < N_NODES * 32; t += 512) {
        int n = t >> 5, c = t & 31;
        xs[t] = (c < RAW_FEAT) ? state[(b * N_NODES + n) * RAW_FEAT + c]
                               : pos[n * 6 + (c - RAW_FEAT)];
    }
    for (int t = tid; t < N_EDGES; t += 512) {
        srcs[t] = (unsigned short)csrc_g[t];
        dsts[t] = (unsigned short)cdst_g[t];
        ewc[t]  = cew_g[t];
    }
    if (tid < 64) eW[tid] = We[tid];
    if (tid < N_NODES + 1) rp_s[tid] = rp_g[tid];
    if (tid < N_NODES) { amaxI[tid] = (int)0x80000000; dens[tid] = 0.f; }
    __syncthreads();

    // ---- q,k,v,skip
    {
        const float4* xs4 = (const float4*)xs;
        const float4* Wq4 = (const float4*)Wq;
        const float4* Wk4 = (const float4*)Wk;
        const float4* Wv4 = (const float4*)Wv;
        const float4* Ws4 = (const float4*)Wsk;
        for (int t = tid; t < N_NODES * 64; t += 512) {
            int n = t >> 6, d = t & 63;
            float aq = bq[d], ak = bk[d], av = bv[d], ask = bsk[d];
            #pragma unroll
            for (int c4 = 0; c4 < 8; ++c4) {
                float4 xv = xs4[n * 8 + c4];
                float4 wq = Wq4[d * 8 + c4];
                float4 wk = Wk4[d * 8 + c4];
                float4 wv = Wv4[d * 8 + c4];
                float4 wsv = Ws4[d * 8 + c4];
                aq += xv.x * wq.x + xv.y * wq.y + xv.z * wq.z + xv.w * wq.w;
                ak += xv.x * wk.x + xv.y * wk.y + xv.z * wk.z + xv.w * wk.w;
                av += xv.x * wv.x + xv.y * wv.y + xv.z * wv.z + xv.w * wv.w;
                ask += xv.x * wsv.x + xv.y * wsv.y + xv.z * wsv.z + xv.w * wsv.w;
            }
            qs [n * 68 + d] = aq;
            kss[n * 68 + d] = ak;
            vss[n * 68 + d] = av;
            o1s[n * 68 + d] = ask;
        }
        if (tid == 511) {
            float s = 0.f;
            #pragma unroll
            for (int n = 0; n < N_NODES; ++n) s += xs[n * 32 + 1];
            ta_ws[b] = s;
        }
    }
    __syncthreads();

    // ---- qWe[n] = dot(q[n], We)
    if (tid < N_NODES) {
        const float4* q4 = (const float4*)(qs + tid * 68);
        const float4* e4 = (const float4*)eW;
        float s = 0.f;
        #pragma unroll
        for (int i = 0; i < 16; ++i) {
            float4 a = q4[i], e = e4[i];
            s += a.x * e.x + a.y * e.y + a.z * e.z + a.w * e.w;
        }
        qWe[tid] = s;
    }
    __syncthreads();

    // ---- pass A: alpha per csr slot; segment max (CSR order => q reads
    //      near-broadcast within a wave: lanes share dst)
    for (int t = tid; t < N_EDGES; t += 512) {
        int s = srcs[t], d = dsts[t];
        const float4* q4 = (const float4*)(qs + d * 68);
        const float4* k4 = (const float4*)(kss + s * 68);
        float dot = 0.f;
        #pragma unroll
        for (int i = 0; i < 16; ++i) {
            float4 a = q4[i], c = k4[i];
            dot += a.x * c.x + a.y * c.y + a.z * c.z + a.w * c.w;
        }
        float al = 0.125f * (dot + ewc[t] * qWe[d]);
        alpha[t] = al;
        int bits = __float_as_int(al);
        int key = bits >= 0 ? bits : (bits ^ 0x7fffffff);
        atomicMax(&amaxI[d], key);
    }
    __syncthreads();

    // ---- pass B: exp + denominator
    for (int t = tid; t < N_EDGES; t += 512) {
        int d = dsts[t];
        int k = amaxI[d];
        float m = __int_as_float(k >= 0 ? k : (k ^ 0x7fffffff));
        float ex = expf(alpha[t] - m);
        alpha[t] = ex;
        atomicAdd(&dens[d], ex);
    }
    __syncthreads();

    // ---- pass B2: alpha <- softmax weight w (in place)
    for (int t = tid; t < N_EDGES; t += 512)
        alpha[t] = alpha[t] / (dens[dsts[t]] + 1e-16f);
    __syncthreads();

    // ---- csum[n] = sum_e w*ew (once per node, not per 16 owners)
    if (tid < N_NODES) {
        float cs = 0.f;
        for (int e = rp_s[tid]; e < rp_s[tid + 1]; ++e) cs += alpha[e] * ewc[e];
        csum_s[tid] = cs;
    }
    __syncthreads();

    // ---- pass C: CSR gather, owner per (node, dd4). Lean inner loop.
    {
        const float4* vss4 = (const float4*)vss;
        const float4* eW4  = (const float4*)eW;
        for (int t = tid; t < N_NODES * 16; t += 512) {
            int n = t >> 4, dd4 = t & 15;
            float4 acc = {0.f, 0.f, 0.f, 0.f};
            int e0 = rp_s[n], e1 = rp_s[n + 1];
            for (int e = e0; e < e1; ++e) {
                float w = alpha[e];
                float4 v = vss4[srcs[e] * 17 + dd4];
                acc.x += w * v.x; acc.y += w * v.y;
                acc.z += w * v.z; acc.w += w * v.w;
            }
            float cs = csum_s[n];
            float4 ev = eW4[dd4];
            int o = n * 68 + dd4 * 4;
            o1s[o + 0] += acc.x + cs * ev.x;
            o1s[o + 1] += acc.y + cs * ev.y;
            o1s[o + 2] += acc.z + cs * ev.z;
            o1s[o + 3] += acc.w + cs * ev.w;
        }
    }
    __syncthreads();

    // ---- out1 = relu(skip + agg)
    for (int t = tid; t < N_NODES * 64; t += 512) {
        int n = t >> 6, d = t & 63;
        out1_ws[(b * N_NODES + n) * 64 + d] = fmaxf(o1s[n * 68 + d], 0.f);
    }
}

// ---------------------------------------------------------------------------
// K23: fused MLP. 64 rows/block, lane=row, wave owns a 64-col quarter.
// W1t/W2t k-major -> wave-uniform rows load via scalar path; VALU does only
// FMAs. h1 never touches HBM: LN1 output written straight into the GEMM2
// A-tile in LDS (overlaying the dead GEMM1 A-tile).
// ---------------------------------------------------------------------------
__global__ __launch_bounds__(256) void k23_mlp(
    const float* __restrict__ state, const float* __restrict__ pos,
    const float* __restrict__ out1_ws, const float* __restrict__ ta_ws,
    const float* __restrict__ W1t, const float* __restrict__ b1,
    const float* __restrict__ g1, const float* __restrict__ be1,
    const float* __restrict__ W2t, const float* __restrict__ b2,
    const float* __restrict__ g2, const float* __restrict__ be2,
    const float* __restrict__ W3, const float* __restrict__ b3,
    float* __restrict__ conc_ws)
{
    __shared__ __align__(16) float smemA[64 * 256];  // GEMM1 A (25/64 used) then h1 tile
    __shared__ float redS[256], redQ[256], redP[256];

    const int tid = threadIdx.x, lane = tid & 63;
    const int wv = __builtin_amdgcn_readfirstlane(threadIdx.x >> 6);
    const int c0 = wv * 64;
    const int m0 = blockIdx.x * 64;

    // ---- stage GEMM1 A-tile: [k4][row][kk], k4 0..24 (k<100, zero-padded)
    for (int t = tid; t < 64 * 100; t += 256) {
        int r = t / 100, k = t - r * 100;
        int m = m0 + r, bb = m / N_NODES, n = m - bb * N_NODES;
        float v;
        if (k < 64)       v = out1_ws[m * 64 + k];
        else if (k == 64) v = ta_ws[bb];
        else if (k < 91)  v = state[m * RAW_FEAT + (k - 65)];
        else if (k < 97)  v = pos[n * 6 + (k - 91)];
        else              v = 0.f;
        smemA[(k >> 2) * 256 + r * 4 + (k & 3)] = v;
    }
    __syncthreads();

    // ---- GEMM1: acc[c] = row(lane) x col(c0+c), K=100
    float acc[64];
    #pragma unroll
    for (int c = 0; c < 64; ++c) acc[c] = 0.f;
    {
        const float4* As4 = (const float4*)smemA;
        for (int k4 = 0; k4 < 25; ++k4) {
            float4 a = As4[k4 * 64 + lane];
            float av[4] = {a.x, a.y, a.z, a.w};
            const float* wbase = W1t + (k4 * 4) * HIDDEN + c0;
            #pragma unroll
            for (int kk = 0; kk < 4; ++kk) {
                const float* wr = wbase + kk * HIDDEN;   // wave-uniform
                #pragma unroll
                for (int c = 0; c < 64; ++c) acc[c] = fmaf(av[kk], wr[c], acc[c]);
            }
        }
    }

    // ---- LN1 stats
    float sm = 0.f, sq = 0.f;
    #pragma unroll
    for (int c = 0; c < 64; ++c) {
        float v = acc[c] + b1[c0 + c];
        acc[c] = v; sm += v; sq += v * v;
    }
    redS[wv * 64 + lane] = sm; redQ[wv * 64 + lane] = sq;
    __syncthreads();                         // also fences GEMM1's A reads
    {
        float S = redS[lane] + redS[64 + lane] + redS[128 + lane] + redS[192 + lane];
        float Q = redQ[lane] + redQ[64 + lane] + redQ[128 + lane] + redQ[192 + lane];
        float mu = S * (1.f / 256.f);
        float rstd = rsqrtf(Q * (1.f / 256.f) - mu * mu + 1e-5f);
        // ---- LN1 + leaky -> h1 tile straight into LDS [k4][row][kk]
        #pragma unroll
        for (int c4 = 0; c4 < 16; ++c4) {
            float4 yv;
            float* yp = (float*)&yv;
            #pragma unroll
            for (int j = 0; j < 4; ++j) {
                int c = c4 * 4 + j, cg = c0 + c;
                float y = (acc[c] - mu) * rstd * g1[cg] + be1[cg];
                yp[j] = y > 0.f ? y : 0.01f * y;
            }
            ((float4*)smemA)[((c0 >> 2) + c4) * 64 + lane] = yv;
        }
    }
    __syncthreads();

    // ---- GEMM2: K=256
    #pragma unroll
    for (int c = 0; c < 64; ++c) acc[c] = 0.f;
    {
        const float4* As4 = (const float4*)smemA;
        for (int k4 = 0; k4 < 64; ++k4) {
            float4 a = As4[k4 * 64 + lane];
            float av[4] = {a.x, a.y, a.z, a.w};
            const float* wbase = W2t + (k4 * 4) * HIDDEN + c0;
            #pragma unroll
            for (int kk = 0; kk < 4; ++kk) {
                const float* wr = wbase + kk * HIDDEN;   // wave-uniform
                #pragma unroll
                for (int c = 0; c < 64; ++c) acc[c] = fmaf(av[kk], wr[c], acc[c]);
            }
        }
    }

    // ---- LN2 stats
    sm = 0.f; sq = 0.f;
    #pragma unroll
    for (int c = 0; c < 64; ++c) {
        float v = acc[c] + b2[c0 + c];
        acc[c] = v; sm += v; sq += v * v;
    }
    redS[wv * 64 + lane] = sm; redQ[wv * 64 + lane] = sq;
    __syncthreads();
    {
        float S = redS[lane] + redS[64 + lane] + redS[128 + lane] + redS[192 + lane];
        float Q = redQ[lane] + redQ[64 + lane] + redQ[128 + lane] + redQ[192 + lane];
        float mu = S * (1.f / 256.f);
        float rstd = rsqrtf(Q * (1.f / 256.f) - mu * mu + 1e-5f);
        float part = 0.f;
        #pragma unroll
        for (int c = 0; c < 64; ++c) {
            int cg = c0 + c;
            float z = (acc[c] - mu) * rstd * g2[cg] + be2[cg];
            z = z > 0.f ? z : 0.01f * z;
            part += z * W3[cg];
        }
        redP[wv * 64 + lane] = part;
    }
    __syncthreads();
    if (wv == 0) {
        float P = redP[lane] + redP[64 + lane] + redP[128 + lane] + redP[192 + lane]
                + b3[0];
        float sp = fmaxf(P, 0.f) + log1pf(expf(-fabsf(P)));   // softplus
        conc_ws[m0 + lane] = sp;
    }
}

// ---------------------------------------------------------------------------
// K4: action = conc / (sum_n conc + 1e-20), per batch
// ---------------------------------------------------------------------------
__global__ __launch_bounds__(128) void k4_norm(
    const float* __restrict__ conc_ws, float* __restrict__ out)
{
    __shared__ float red[128];
    const int b = blockIdx.x, tid = threadIdx.x;
    float v = 0.f;
    if (tid < N_NODES) v = conc_ws[b * N_NODES + tid];
    red[tid] = v;
    __syncthreads();
    for (int off = 64; off >= 1; off >>= 1) {
        if (tid < off) red[tid] += red[tid + off];
        __syncthreads();
    }
    float s = red[0];
    if (tid < N_NODES) out[b * N_NODES + tid] = v / (s + 1e-20f);
}

extern "C" void kernel_launch(void* const* d_in, const int* in_sizes, int n_in,
                              void* d_out, int out_size, void* d_ws, size_t ws_size,
                              hipStream_t stream) {
    const float* state = (const float*)d_in[0];
    const float* pos   = (const float*)d_in[1];
    const float* ew    = (const float*)d_in[2];
    const float* Wq  = (const float*)d_in[3];  const float* bq  = (const float*)d_in[4];
    const float* Wk  = (const float*)d_in[5];  const float* bk  = (const float*)d_in[6];
    const float* Wv  = (const float*)d_in[7];  const float* bv  = (const float*)d_in[8];
    const float* We  = (const float*)d_in[9];
    const float* Wsk = (const float*)d_in[10]; const float* bsk = (const float*)d_in[11];
    const float* W1  = (const float*)d_in[12]; const float* b1  = (const float*)d_in[13];
    const float* g1  = (const float*)d_in[14]; const float* be1 = (const float*)d_in[15];
    const float* W2  = (const float*)d_in[16]; const float* b2  = (const float*)d_in[17];
    const float* g2  = (const float*)d_in[18]; const float* be2 = (const float*)d_in[19];
    const float* W3  = (const float*)d_in[20]; const float* b3  = (const float*)d_in[21];
    const int*   ei  = (const int*)d_in[22];

    float* ws   = (float*)d_ws;
    float* ta   = ws;                                  // 256
    float* out1 = ws + 256;                            // M*64
    float* conc = out1 + (size_t)M_ROWS * 64;          // M
    float* W1t  = conc + M_ROWS;                       // 100*256
    float* W2t  = W1t + 100 * HIDDEN;                  // 256*256
    int*   rp   = (int*)(W2t + HIDDEN * HIDDEN);       // 80
    int*   csrc = rp + 80;                             // 3000
    int*   cdst = csrc + N_EDGES;                      // 3000
    float* cew  = (float*)(cdst + N_EDGES);            // 3000
    float* out  = (float*)d_out;

    k_prep<<<dim3(25), dim3(256), 0, stream>>>(
        W1, W2, ei, ew, W1t, W2t, rp, csrc, cdst, cew);
    k1_conv<<<dim3(BATCH), dim3(512), 0, stream>>>(
        state, pos, rp, csrc, cdst, cew,
        Wq, bq, Wk, bk, Wv, bv, We, Wsk, bsk, out1, ta);
    k23_mlp<<<dim3(M_ROWS / 64), dim3(256), 0, stream>>>(
        state, pos, out1, ta, W1t, b1, g1, be1,
        W2t, b2, g2, be2, W3, b3, conc);
    k4_norm<<<dim3(BATCH), dim3(128), 0, stream>>>(conc, out);
}